// Round 3
// baseline (862.109 us; speedup 1.0000x reference)
//
#include <hip/hip_runtime.h>
#include <hip/hip_bf16.h>

// B=2,H=16,S=2048,D=64 fp32 attention returning (output, attention).
// v4: BARRIER-FREE main kernel. K (bf16 [key][d]) and V^T (bf16 [d][key]) in
//     d_ws are already in MFMA fragment layout -> lanes load 16B fragments
//     directly from global (L1/L2-resident, 256KB/head) instead of LDS staging.
//     Q fragments loaded directly per lane. Only LDS use is the 16KB fp32
//     P-tile, restricted to each wave's own 16 rows (same-wave RAW only) with
//     an XOR chunk-swizzle for conflict-free b128. Zero __syncthreads().
//     Coalesced 256B-per-row nontemporal P store kept from v3.

#define S_LEN 2048
#define D_DIM 64
#define BM 64
#define BN 64
#define NT (S_LEN / BN)   // 32 key tiles
#define LDP 72            // (fallback kernel only) padded bf16 row stride
#define BH_N 32

typedef __attribute__((ext_vector_type(8))) short bf16x8;
typedef __attribute__((ext_vector_type(4))) float f32x4;

__device__ __forceinline__ unsigned pack_bf16(float a, float b) {
    union { __hip_bfloat162 h; unsigned u; } cv;
    cv.h = __float22bfloat162_rn(make_float2(a, b));   // v_cvt_pk_bf16_f32
    return cv.u;
}
__device__ __forceinline__ unsigned short bf1(float x) {
    union { __hip_bfloat16 h; unsigned short u; } cv;
    cv.h = __float2bfloat16(x);
    return cv.u;
}

// Pf tile: 64 rows x 16 float4-chunks, chunk XOR-swizzled by row so that
// quarter-wave access patterns (write: fixed chunk/varying row; read: fixed
// row-group/varying chunk) both spread across all 32 banks.
__device__ __forceinline__ float* pf_ptr(float* Pf, int row, int chunk) {
    return Pf + row * 64 + ((chunk ^ (row & 7)) << 2);
}

// ---- prepass: K fp32 -> bf16, same layout [bh][key][d] ----
__global__ __launch_bounds__(256)
void conv_k(const float* __restrict__ Kg, unsigned short* __restrict__ Kw) {
    size_t i = (size_t)(blockIdx.x * 256 + threadIdx.x) * 8;
    const float4 v0 = *(const float4*)(Kg + i);
    const float4 v1 = *(const float4*)(Kg + i + 4);
    uint4 o;
    o.x = pack_bf16(v0.x, v0.y);
    o.y = pack_bf16(v0.z, v0.w);
    o.z = pack_bf16(v1.x, v1.y);
    o.w = pack_bf16(v1.z, v1.w);
    *(uint4*)(Kw + i) = o;
}

// ---- prepass: V fp32 [bh][key][d] -> bf16 transposed [bh][d][key] ----
__global__ __launch_bounds__(256)
void conv_vt(const float* __restrict__ Vg, unsigned short* __restrict__ Vtw) {
    const int bh = blockIdx.y;
    const int d  = threadIdx.x & 63;
    const int kq = threadIdx.x >> 6;
    const int key0 = blockIdx.x * 32 + kq * 8;
    const float* Vb = Vg + ((size_t)bh * S_LEN + key0) * D_DIM + d;
    float f[8];
    #pragma unroll
    for (int i = 0; i < 8; ++i) f[i] = Vb[i * D_DIM];   // coalesced across d
    uint4 o;
    o.x = pack_bf16(f[0], f[1]);
    o.y = pack_bf16(f[2], f[3]);
    o.z = pack_bf16(f[4], f[5]);
    o.w = pack_bf16(f[6], f[7]);
    *(uint4*)(Vtw + ((size_t)bh * D_DIM + d) * S_LEN + key0) = o;
}

// ================= v4 fast kernel: barrier-free =================
__global__ __launch_bounds__(256, 4)
void attn_fast(const float* __restrict__ Qg, const int* __restrict__ Mg,
               const unsigned short* __restrict__ Kw,
               const unsigned short* __restrict__ Vtw,
               float* __restrict__ Og, float* __restrict__ Ag) {
    __shared__ float Pf[BM * 64];   // 16 KB, per-wave-private 16-row slabs

    const int tid  = threadIdx.x;
    const int w    = tid >> 6;
    const int lane = tid & 63;
    const int l15  = lane & 15;
    const int quad = lane >> 4;

    const int qt = blockIdx.x;
    const int bh = blockIdx.y;
    const int b  = bh >> 4;
    const int q0 = qt * BM;
    const int qrow = w * 16 + l15;     // this lane's q row within the tile

    const float* Qb = Qg + ((size_t)bh * S_LEN + q0) * D_DIM;
    const int*   Mb = Mg + (size_t)b * S_LEN;
    float* Ob = Og + ((size_t)bh * S_LEN + q0) * D_DIM;
    float* Ab = Ag + ((size_t)bh * S_LEN + q0) * (size_t)S_LEN;

    const unsigned short* Kb = Kw  + (size_t)bh * S_LEN * D_DIM;  // [key][d]
    const unsigned short* Vb = Vtw + (size_t)bh * D_DIM * S_LEN;  // [d][key]

    // ---- Q fragments direct from global, scaled by log2(e)/32 ----
    bf16x8 aq[2];
    {
        const float sc = 0.04508422f;  // log2(e)/32 : folds temperature + exp->exp2
        #pragma unroll
        for (int ks = 0; ks < 2; ++ks) {
            const float* qp = Qb + qrow * D_DIM + ks * 32 + quad * 8;
            const float4 a = *(const float4*)(qp);
            const float4 c = *(const float4*)(qp + 4);
            union { bf16x8 v; uint4 u; } cv;
            cv.u.x = pack_bf16(a.x * sc, a.y * sc);
            cv.u.y = pack_bf16(a.z * sc, a.w * sc);
            cv.u.z = pack_bf16(c.x * sc, c.y * sc);
            cv.u.w = pack_bf16(c.z * sc, c.w * sc);
            aq[ks] = cv.v;
        }
    }

    const int koff = l15 * D_DIM + quad * 8;          // K fragment lane offset
    const size_t vbase = (size_t)l15 * S_LEN + quad * 8;  // V^T fragment lane offset

    // ================= Pass 1: row sums of exp2(s), no LDS, no barriers ======
    float lsum = 0.f;
    for (int kt = 0; kt < NT; ++kt) {
        const unsigned short* Kt = Kb + (size_t)kt * BN * D_DIM + koff;
        const int* Mt = Mb + kt * BN + quad * 4;
        #pragma unroll
        for (int cb = 0; cb < 4; ++cb) {
            f32x4 acc = {0.f, 0.f, 0.f, 0.f};
            #pragma unroll
            for (int ks = 0; ks < 2; ++ks) {
                bf16x8 bk = *(const bf16x8*)(Kt + cb * (16 * D_DIM) + ks * 32);
                acc = __builtin_amdgcn_mfma_f32_16x16x32_bf16(bk, aq[ks], acc, 0, 0, 0);
            }
            const int4 m4 = *(const int4*)(Mt + cb * 16);
            float e0 = m4.x ? __builtin_exp2f(acc[0]) : 0.f;
            float e1 = m4.y ? __builtin_exp2f(acc[1]) : 0.f;
            float e2 = m4.z ? __builtin_exp2f(acc[2]) : 0.f;
            float e3 = m4.w ? __builtin_exp2f(acc[3]) : 0.f;
            lsum += (e0 + e1) + (e2 + e3);
        }
    }
    // quads hold disjoint key subsets of the SAME q row -> 2-shuffle reduce
    lsum += __shfl_xor(lsum, 16);
    lsum += __shfl_xor(lsum, 32);
    const float linv = 1.0f / lsum;

    // ================= Pass 2: P tiles + O = P V, still no barriers ==========
    f32x4 oacc[4];
    #pragma unroll
    for (int db = 0; db < 4; ++db) oacc[db] = (f32x4){0.f, 0.f, 0.f, 0.f};

    for (int kt = 0; kt < NT; ++kt) {
        const int key0 = kt * BN;
        const unsigned short* Kt = Kb + (size_t)key0 * D_DIM + koff;
        const int* Mt = Mb + key0 + quad * 4;

        // QK^T -> exp2 -> normalized P into own Pf rows (swizzled chunks)
        #pragma unroll
        for (int cb = 0; cb < 4; ++cb) {
            f32x4 acc = {0.f, 0.f, 0.f, 0.f};
            #pragma unroll
            for (int ks = 0; ks < 2; ++ks) {
                bf16x8 bk = *(const bf16x8*)(Kt + cb * (16 * D_DIM) + ks * 32);
                acc = __builtin_amdgcn_mfma_f32_16x16x32_bf16(bk, aq[ks], acc, 0, 0, 0);
            }
            const int4 m4 = *(const int4*)(Mt + cb * 16);
            f32x4 p;
            p[0] = (m4.x ? __builtin_exp2f(acc[0]) : 0.f) * linv;
            p[1] = (m4.y ? __builtin_exp2f(acc[1]) : 0.f) * linv;
            p[2] = (m4.z ? __builtin_exp2f(acc[2]) : 0.f) * linv;
            p[3] = (m4.w ? __builtin_exp2f(acc[3]) : 0.f) * linv;
            *(f32x4*)pf_ptr(Pf, qrow, cb * 4 + quad) = p;
        }

        // PV: A = V^T fragment direct from global, B = P fragment packed from
        // this wave's own Pf rows (same-wave RAW -> compiler lgkmcnt, no barrier).
        #pragma unroll
        for (int ks2 = 0; ks2 < 2; ++ks2) {
            const f32x4 pa = *(const f32x4*)pf_ptr(Pf, qrow, ks2 * 8 + quad * 2);
            const f32x4 pb = *(const f32x4*)pf_ptr(Pf, qrow, ks2 * 8 + quad * 2 + 1);
            union { bf16x8 v; uint4 u; } ap;
            ap.u.x = pack_bf16(pa[0], pa[1]);
            ap.u.y = pack_bf16(pa[2], pa[3]);
            ap.u.z = pack_bf16(pb[0], pb[1]);
            ap.u.w = pack_bf16(pb[2], pb[3]);
            const unsigned short* Vt = Vb + vbase + key0 + ks2 * 32;
            #pragma unroll
            for (int db = 0; db < 4; ++db) {
                bf16x8 bv = *(const bf16x8*)(Vt + (size_t)db * (16 * S_LEN));
                oacc[db] = __builtin_amdgcn_mfma_f32_16x16x32_bf16(bv, ap.v, oacc[db], 0, 0, 0);
            }
        }

        // Coalesced P store of this wave's OWN 16 rows: each wave instruction
        // covers 4 rows x 256B contiguous segments. No barrier needed.
        #pragma unroll
        for (int i = 0; i < 4; ++i) {
            const int row = w * 16 + i * 4 + quad;
            f32x4 t = *(const f32x4*)pf_ptr(Pf, row, l15);
            __builtin_nontemporal_store(
                t, (f32x4*)(Ab + (size_t)row * S_LEN + key0 + l15 * 4));
        }
    }

    // write O: lane holds d = db*16 + quad*4 + r for row qrow -> float4 stores
    #pragma unroll
    for (int db = 0; db < 4; ++db) {
        f32x4 o4 = oacc[db];
        __builtin_nontemporal_store(
            o4, (f32x4*)(Ob + (size_t)qrow * D_DIM + db * 16 + quad * 4));
    }
}

// ================= fallback (no workspace): v3 staged kernel =================
__global__ __launch_bounds__(256, 4)
void attn_fallback(const float* __restrict__ Qg, const float* __restrict__ Kg,
                   const float* __restrict__ Vg, const int* __restrict__ Mg,
                   float* __restrict__ Og, float* __restrict__ Ag) {
    __shared__ unsigned short Ks[BN * LDP];
    __shared__ unsigned short QV[D_DIM * LDP];
    __shared__ float Pf[BM * 68];
    __shared__ int maskS[BN];

    const int tid  = threadIdx.x;
    const int w    = tid >> 6;
    const int lane = tid & 63;
    const int l15  = lane & 15;
    const int quad = lane >> 4;

    const int qt = blockIdx.x;
    const int bh = blockIdx.y;
    const int b  = bh >> 4;
    const int q0 = qt * BM;
    const int qrow = w * 16 + l15;

    const float* Qb = Qg + ((size_t)bh * S_LEN + q0) * D_DIM;
    const int*   Mb = Mg + (size_t)b * S_LEN;
    float* Ob = Og + ((size_t)bh * S_LEN + q0) * D_DIM;
    float* Ab = Ag + ((size_t)bh * S_LEN + q0) * (size_t)S_LEN;

    {
        const float sc = 0.04508422f;
        #pragma unroll
        for (int i = 0; i < 4; ++i) {
            int f = tid + i * 256;
            int row = f >> 4, c4 = f & 15;
            const float4 v = *(const float4*)(Qb + row * D_DIM + c4 * 4);
            *(uint2*)(&QV[row * LDP + c4 * 4]) =
                make_uint2(pack_bf16(v.x * sc, v.y * sc), pack_bf16(v.z * sc, v.w * sc));
        }
    }
    __syncthreads();

    bf16x8 aq[2];
    #pragma unroll
    for (int ks = 0; ks < 2; ++ks)
        aq[ks] = *(const bf16x8*)(&QV[qrow * LDP + ks * 32 + quad * 8]);

    auto stage_k = [&](int key0) {
        const float* Kb = Kg + ((size_t)bh * S_LEN + key0) * D_DIM;
        #pragma unroll
        for (int i = 0; i < 4; ++i) {
            int f = tid + i * 256;
            int row = f >> 4, c4 = f & 15;
            const float4 v = *(const float4*)(Kb + row * D_DIM + c4 * 4);
            *(uint2*)(&Ks[row * LDP + c4 * 4]) =
                make_uint2(pack_bf16(v.x, v.y), pack_bf16(v.z, v.w));
        }
    };

    float lsum = 0.f;
    for (int kt = 0; kt < NT; ++kt) {
        const int key0 = kt * BN;
        stage_k(key0);
        if (tid < BN) maskS[tid] = Mb[key0 + tid];
        __syncthreads();
        #pragma unroll
        for (int cb = 0; cb < 4; ++cb) {
            f32x4 acc = {0.f, 0.f, 0.f, 0.f};
            #pragma unroll
            for (int ks = 0; ks < 2; ++ks) {
                bf16x8 bk = *(const bf16x8*)(&Ks[(cb * 16 + l15) * LDP + ks * 32 + quad * 8]);
                acc = __builtin_amdgcn_mfma_f32_16x16x32_bf16(bk, aq[ks], acc, 0, 0, 0);
            }
            const int4 m4 = *(const int4*)(&maskS[cb * 16 + quad * 4]);
            float e0 = m4.x ? __builtin_exp2f(acc[0]) : 0.f;
            float e1 = m4.y ? __builtin_exp2f(acc[1]) : 0.f;
            float e2 = m4.z ? __builtin_exp2f(acc[2]) : 0.f;
            float e3 = m4.w ? __builtin_exp2f(acc[3]) : 0.f;
            lsum += (e0 + e1) + (e2 + e3);
        }
        __syncthreads();
    }
    lsum += __shfl_xor(lsum, 16);
    lsum += __shfl_xor(lsum, 32);
    const float linv = 1.0f / lsum;

    f32x4 oacc[4];
    #pragma unroll
    for (int db = 0; db < 4; ++db) oacc[db] = (f32x4){0.f, 0.f, 0.f, 0.f};

    for (int kt = 0; kt < NT; ++kt) {
        const int key0 = kt * BN;
        stage_k(key0);
        {
            int key = tid & 63, g = tid >> 6;
            #pragma unroll
            for (int i = 0; i < 4; ++i) {
                int d0 = (g * 4 + i) * 4;
                const float4 v = *(const float4*)(Vg + ((size_t)bh * S_LEN + key0 + key) * D_DIM + d0);
                QV[(d0 + 0) * LDP + key] = bf1(v.x);
                QV[(d0 + 1) * LDP + key] = bf1(v.y);
                QV[(d0 + 2) * LDP + key] = bf1(v.z);
                QV[(d0 + 3) * LDP + key] = bf1(v.w);
            }
        }
        if (tid < BN) maskS[tid] = Mb[key0 + tid];
        __syncthreads();

        #pragma unroll
        for (int cb = 0; cb < 4; ++cb) {
            f32x4 acc = {0.f, 0.f, 0.f, 0.f};
            #pragma unroll
            for (int ks = 0; ks < 2; ++ks) {
                bf16x8 bk = *(const bf16x8*)(&Ks[(cb * 16 + l15) * LDP + ks * 32 + quad * 8]);
                acc = __builtin_amdgcn_mfma_f32_16x16x32_bf16(bk, aq[ks], acc, 0, 0, 0);
            }
            const int4 m4 = *(const int4*)(&maskS[cb * 16 + quad * 4]);
            f32x4 p;
            p[0] = (m4.x ? __builtin_exp2f(acc[0]) : 0.f) * linv;
            p[1] = (m4.y ? __builtin_exp2f(acc[1]) : 0.f) * linv;
            p[2] = (m4.z ? __builtin_exp2f(acc[2]) : 0.f) * linv;
            p[3] = (m4.w ? __builtin_exp2f(acc[3]) : 0.f) * linv;
            *(f32x4*)(&Pf[qrow * 68 + cb * 16 + quad * 4]) = p;
        }
        #pragma unroll
        for (int ks2 = 0; ks2 < 2; ++ks2) {
            const float* pr = &Pf[qrow * 68 + ks2 * 32 + quad * 8];
            f32x4 pa = *(const f32x4*)(pr);
            f32x4 pb = *(const f32x4*)(pr + 4);
            union { bf16x8 v; uint4 u; } ap;
            ap.u.x = pack_bf16(pa[0], pa[1]);
            ap.u.y = pack_bf16(pa[2], pa[3]);
            ap.u.z = pack_bf16(pb[0], pb[1]);
            ap.u.w = pack_bf16(pb[2], pb[3]);
            #pragma unroll
            for (int db = 0; db < 4; ++db) {
                bf16x8 bv = *(const bf16x8*)(&QV[(db * 16 + l15) * LDP + ks2 * 32 + quad * 8]);
                oacc[db] = __builtin_amdgcn_mfma_f32_16x16x32_bf16(bv, ap.v, oacc[db], 0, 0, 0);
            }
        }
        __syncthreads();
        #pragma unroll
        for (int i = 0; i < 4; ++i) {
            int idx = tid + i * 256;
            int row = idx >> 4, c4 = idx & 15;
            f32x4 t = *(const f32x4*)(&Pf[row * 68 + c4 * 4]);
            __builtin_nontemporal_store(
                t, (f32x4*)(Ab + (size_t)row * S_LEN + key0 + c4 * 4));
        }
    }

    #pragma unroll
    for (int db = 0; db < 4; ++db) {
        f32x4 o4 = oacc[db];
        __builtin_nontemporal_store(
            o4, (f32x4*)(Ob + (size_t)qrow * D_DIM + db * 16 + quad * 4));
    }
}

extern "C" void kernel_launch(void* const* d_in, const int* in_sizes, int n_in,
                              void* d_out, int out_size, void* d_ws, size_t ws_size,
                              hipStream_t stream) {
    const float* q = (const float*)d_in[0];
    const float* k = (const float*)d_in[1];
    const float* v = (const float*)d_in[2];
    const int* mask = (const int*)d_in[3];
    float* out = (float*)d_out;                         // [B,H,S,D]
    float* attn = out + (size_t)2 * 16 * 2048 * 64;     // [B,H,S,S]

    const size_t kw_elems = (size_t)BH_N * S_LEN * D_DIM;        // 4.19M bf16
    const size_t need = 2 * kw_elems * sizeof(unsigned short);   // 16.8 MB
    dim3 block(256);
    dim3 grid(S_LEN / BM, BH_N);

    if (d_ws && ws_size >= need) {
        unsigned short* Kw  = (unsigned short*)d_ws;
        unsigned short* Vtw = Kw + kw_elems;
        conv_k<<<dim3((unsigned)(kw_elems / 8 / 256)), block, 0, stream>>>(k, Kw);
        conv_vt<<<dim3(S_LEN / 32, BH_N), block, 0, stream>>>(v, Vtw);
        attn_fast<<<grid, block, 0, stream>>>(q, mask, Kw, Vtw, out, attn);
    } else {
        attn_fallback<<<grid, block, 0, stream>>>(q, k, v, mask, out, attn);
    }
}

// Round 4
// 747.316 us; speedup vs baseline: 1.1536x; 1.1536x over previous
//
#include <hip/hip_runtime.h>
#include <hip/hip_bf16.h>

// B=2,H=16,S=2048,D=64 fp32 attention returning (output, attention).
// v5: back to v3's cooperative staged structure (v4's barrier-free direct-global
//     was latency-bound: MfmaUtil 5%, VALUBusy 21%), now software-pipelined:
//     each key tile = K-phase (QK^T->exp->Pf) + V-phase (PV + coalesced P store),
//     ONE barrier per phase, global loads for the next phase issued reg-staged
//     right after each barrier (T14) so L2/HBM latency hides under compute.
//     K stages into KV[0], V^T into KV[1] (stable double-buffer). Tiles are
//     XOR-chunk-swizzled (write AND read side) -> 8KB each, no padding; LDS
//     total 33.8KB -> 4 blocks/CU. P store per-wave-private (own 16 rows,
//     4 rows x 256B segments per instruction). Prepass K->bf16, V->bf16^T kept.

#define S_LEN 2048
#define D_DIM 64
#define BM 64
#define BN 64
#define NT (S_LEN / BN)   // 32 key tiles
#define LDF 68            // fp32 P row stride (272 B -> <=2-way banks)
#define LDP 72            // fallback kernel bf16 row stride
#define BH_N 32

typedef __attribute__((ext_vector_type(8))) short bf16x8;
typedef __attribute__((ext_vector_type(4))) float f32x4;

__device__ __forceinline__ unsigned pack_bf16(float a, float b) {
    union { __hip_bfloat162 h; unsigned u; } cv;
    cv.h = __float22bfloat162_rn(make_float2(a, b));   // v_cvt_pk_bf16_f32
    return cv.u;
}
__device__ __forceinline__ unsigned short bf1(float x) {
    union { __hip_bfloat16 h; unsigned short u; } cv;
    cv.h = __float2bfloat16(x);
    return cv.u;
}

// 64x64 bf16 tile (128B rows), XOR chunk-swizzle: chunk c of row r lives at
// chunk c^(r&7). Returns ushort-element offset; 16B aligned for b128 ops.
// Write side and read side both use this (both-sides-or-neither rule).
__device__ __forceinline__ int tile_off(int row, int c) {
    return row * 64 + ((c ^ (row & 7)) << 3);
}

// ---- prepass: K fp32 -> bf16, same layout [bh][key][d] ----
__global__ __launch_bounds__(256)
void conv_k(const float* __restrict__ Kg, unsigned short* __restrict__ Kw) {
    size_t i = (size_t)(blockIdx.x * 256 + threadIdx.x) * 8;
    const float4 v0 = *(const float4*)(Kg + i);
    const float4 v1 = *(const float4*)(Kg + i + 4);
    uint4 o;
    o.x = pack_bf16(v0.x, v0.y);
    o.y = pack_bf16(v0.z, v0.w);
    o.z = pack_bf16(v1.x, v1.y);
    o.w = pack_bf16(v1.z, v1.w);
    *(uint4*)(Kw + i) = o;
}

// ---- prepass: V fp32 [bh][key][d] -> bf16 transposed [bh][d][key] ----
__global__ __launch_bounds__(256)
void conv_vt(const float* __restrict__ Vg, unsigned short* __restrict__ Vtw) {
    const int bh = blockIdx.y;
    const int d  = threadIdx.x & 63;
    const int kq = threadIdx.x >> 6;
    const int key0 = blockIdx.x * 32 + kq * 8;
    const float* Vb = Vg + ((size_t)bh * S_LEN + key0) * D_DIM + d;
    float f[8];
    #pragma unroll
    for (int i = 0; i < 8; ++i) f[i] = Vb[i * D_DIM];   // coalesced across d
    uint4 o;
    o.x = pack_bf16(f[0], f[1]);
    o.y = pack_bf16(f[2], f[3]);
    o.z = pack_bf16(f[4], f[5]);
    o.w = pack_bf16(f[6], f[7]);
    *(uint4*)(Vtw + ((size_t)bh * D_DIM + d) * S_LEN + key0) = o;
}

// ================= v5 fast kernel: pipelined 2-phase =================
__global__ __launch_bounds__(256, 4)
void attn_fast(const float* __restrict__ Qg, const int* __restrict__ Mg,
               const unsigned short* __restrict__ Kw,
               const unsigned short* __restrict__ Vtw,
               float* __restrict__ Og, float* __restrict__ Ag) {
    __shared__ unsigned short KV[2][64 * 64];   // [0]=K tile, [1]=V^T tile, 8KB each
    __shared__ float Pf[BM * LDF];              // 17408B fp32 P tile

    const int tid  = threadIdx.x;
    const int w    = tid >> 6;
    const int lane = tid & 63;
    const int l15  = lane & 15;
    const int quad = lane >> 4;

    const int qt = blockIdx.x;
    const int bh = blockIdx.y;
    const int b  = bh >> 4;
    const int q0 = qt * BM;
    const int qrow = w * 16 + l15;     // this lane's q row within the tile

    const float* Qb = Qg + ((size_t)bh * S_LEN + q0) * D_DIM;
    const int*   Mb = Mg + (size_t)b * S_LEN;
    float* Ob = Og + ((size_t)bh * S_LEN + q0) * D_DIM;
    float* Ab = Ag + ((size_t)bh * S_LEN + q0) * (size_t)S_LEN;

    const unsigned short* Kb = Kw  + (size_t)bh * S_LEN * D_DIM;  // [key][d]
    const unsigned short* Vb = Vtw + (size_t)bh * D_DIM * S_LEN;  // [d][key]

    // staging geometry: 512 uint4 chunks/tile; thread stages rows srow, srow+32
    const int srow = tid >> 3;      // 0..31
    const int sc   = tid & 7;       // chunk within 128B row

    // ---- Q fragments direct from global, scaled by log2(e)/32 ----
    bf16x8 aq[2];
    {
        const float sc2 = 0.04508422f;  // log2(e)/32: folds temperature + exp->exp2
        #pragma unroll
        for (int ks = 0; ks < 2; ++ks) {
            const float* qp = Qb + qrow * D_DIM + ks * 32 + quad * 8;
            const float4 a = *(const float4*)(qp);
            const float4 c = *(const float4*)(qp + 4);
            union { bf16x8 v; uint4 u; } cv;
            cv.u.x = pack_bf16(a.x * sc2, a.y * sc2);
            cv.u.y = pack_bf16(a.z * sc2, a.w * sc2);
            cv.u.z = pack_bf16(c.x * sc2, c.y * sc2);
            cv.u.w = pack_bf16(c.z * sc2, c.w * sc2);
            aq[ks] = cv.v;
        }
    }

    uint4 rk[2], rv[2];
    auto issueK = [&](int t) {
        const unsigned short* p = Kb + (size_t)(t * BN + srow) * D_DIM + sc * 8;
        rk[0] = *(const uint4*)p;
        rk[1] = *(const uint4*)(p + 32 * D_DIM);
    };
    auto issueV = [&](int t) {
        const unsigned short* p = Vb + (size_t)srow * S_LEN + t * BN + sc * 8;
        rv[0] = *(const uint4*)p;
        rv[1] = *(const uint4*)(p + (size_t)32 * S_LEN);
    };
    auto writeK = [&]() {
        *(uint4*)(&KV[0][tile_off(srow,      sc)]) = rk[0];
        *(uint4*)(&KV[0][tile_off(srow + 32, sc)]) = rk[1];
    };
    auto writeV = [&]() {
        *(uint4*)(&KV[1][tile_off(srow,      sc)]) = rv[0];
        *(uint4*)(&KV[1][tile_off(srow + 32, sc)]) = rv[1];
    };

    // ================= Pass 1: row sums of exp2(s) =================
    // K-only pipeline, alternating KV[t&1], one barrier per tile.
    float lsum = 0.f;
    issueK(0);
    for (int t = 0; t < NT; ++t) {
        const unsigned short* Kt = &KV[t & 1][0];
        {   // write stage (vmcnt auto-inserted), then single barrier
            *(uint4*)(&KV[t & 1][tile_off(srow,      sc)]) = rk[0];
            *(uint4*)(&KV[t & 1][tile_off(srow + 32, sc)]) = rk[1];
        }
        __syncthreads();
        if (t + 1 < NT) issueK(t + 1);   // latency hides under this tile's compute

        const int* Mt = Mb + t * BN + quad * 4;
        #pragma unroll
        for (int cb = 0; cb < 4; ++cb) {
            f32x4 acc = {0.f, 0.f, 0.f, 0.f};
            #pragma unroll
            for (int ks = 0; ks < 2; ++ks) {
                bf16x8 bk = *(const bf16x8*)(Kt + tile_off(cb * 16 + l15, ks * 4 + quad));
                acc = __builtin_amdgcn_mfma_f32_16x16x32_bf16(bk, aq[ks], acc, 0, 0, 0);
            }
            const int4 m4 = *(const int4*)(Mt + cb * 16);
            float e0 = m4.x ? __builtin_exp2f(acc[0]) : 0.f;
            float e1 = m4.y ? __builtin_exp2f(acc[1]) : 0.f;
            float e2 = m4.z ? __builtin_exp2f(acc[2]) : 0.f;
            float e3 = m4.w ? __builtin_exp2f(acc[3]) : 0.f;
            lsum += (e0 + e1) + (e2 + e3);
        }
        // no trailing barrier: next writeStage targets the other buffer, and the
        // per-tile barrier above orders reads of tile t-1 before writes of t+1.
    }
    // quads hold disjoint key subsets of the SAME q row -> 2-shuffle reduce
    lsum += __shfl_xor(lsum, 16);
    lsum += __shfl_xor(lsum, 32);
    const float linv = 1.0f / lsum;

    // ================= Pass 2: K-phase / V-phase pipeline =================
    f32x4 oacc[4];
    #pragma unroll
    for (int db = 0; db < 4; ++db) oacc[db] = (f32x4){0.f, 0.f, 0.f, 0.f};

    issueK(0);
    for (int t = 0; t < NT; ++t) {
        const int key0 = t * BN;
        const int* Mt = Mb + key0 + quad * 4;

        // ---------- K phase: QK^T -> exp2 -> Pf (own rows) ----------
        writeK();                 // KV[0]; prior readers done (barrier of V-phase t-1)
        __syncthreads();
        issueV(t);                // hides under QK compute

        #pragma unroll
        for (int cb = 0; cb < 4; ++cb) {
            f32x4 acc = {0.f, 0.f, 0.f, 0.f};
            #pragma unroll
            for (int ks = 0; ks < 2; ++ks) {
                bf16x8 bk = *(const bf16x8*)(&KV[0][tile_off(cb * 16 + l15, ks * 4 + quad)]);
                acc = __builtin_amdgcn_mfma_f32_16x16x32_bf16(bk, aq[ks], acc, 0, 0, 0);
            }
            const int4 m4 = *(const int4*)(Mt + cb * 16);
            f32x4 p;
            p[0] = (m4.x ? __builtin_exp2f(acc[0]) : 0.f) * linv;
            p[1] = (m4.y ? __builtin_exp2f(acc[1]) : 0.f) * linv;
            p[2] = (m4.z ? __builtin_exp2f(acc[2]) : 0.f) * linv;
            p[3] = (m4.w ? __builtin_exp2f(acc[3]) : 0.f) * linv;
            *(f32x4*)(&Pf[qrow * LDF + (cb * 4 + quad) * 4]) = p;
        }

        // ---------- V phase: PV + coalesced per-wave P store ----------
        writeV();                 // KV[1]; prior readers done (barrier of K-phase t)
        __syncthreads();
        if (t + 1 < NT) issueK(t + 1);   // hides under PV + store

        #pragma unroll
        for (int ks2 = 0; ks2 < 2; ++ks2) {
            const float* pr = &Pf[qrow * LDF + ks2 * 32 + quad * 8];
            f32x4 pa = *(const f32x4*)(pr);
            f32x4 pb = *(const f32x4*)(pr + 4);
            union { bf16x8 v; uint4 u; } ap;
            ap.u.x = pack_bf16(pa[0], pa[1]);
            ap.u.y = pack_bf16(pa[2], pa[3]);
            ap.u.z = pack_bf16(pb[0], pb[1]);
            ap.u.w = pack_bf16(pb[2], pb[3]);
            #pragma unroll
            for (int db = 0; db < 4; ++db) {
                bf16x8 bv = *(const bf16x8*)(&KV[1][tile_off(db * 16 + l15, ks2 * 4 + quad)]);
                oacc[db] = __builtin_amdgcn_mfma_f32_16x16x32_bf16(bv, ap.v, oacc[db], 0, 0, 0);
            }
        }
        // store this wave's OWN 16 rows: 4 rows x 256B contiguous per instruction
        #pragma unroll
        for (int i = 0; i < 4; ++i) {
            const int row = w * 16 + i * 4 + quad;
            f32x4 tv = *(const f32x4*)(&Pf[row * LDF + l15 * 4]);
            __builtin_nontemporal_store(
                tv, (f32x4*)(Ab + (size_t)row * S_LEN + key0 + l15 * 4));
        }
        // Pf rewritten next K-phase by the same wave only -> program order, safe.
    }

    // write O: lane holds d = db*16 + quad*4 + r for row qrow -> float4 stores
    #pragma unroll
    for (int db = 0; db < 4; ++db) {
        f32x4 o4 = oacc[db];
        __builtin_nontemporal_store(
            o4, (f32x4*)(Ob + (size_t)qrow * D_DIM + db * 16 + quad * 4));
    }
}

// ================= fallback (no workspace): v3 staged kernel =================
__global__ __launch_bounds__(256, 4)
void attn_fallback(const float* __restrict__ Qg, const float* __restrict__ Kg,
                   const float* __restrict__ Vg, const int* __restrict__ Mg,
                   float* __restrict__ Og, float* __restrict__ Ag) {
    __shared__ unsigned short Ks[BN * LDP];
    __shared__ unsigned short QV[D_DIM * LDP];
    __shared__ float Pf[BM * 68];
    __shared__ int maskS[BN];

    const int tid  = threadIdx.x;
    const int w    = tid >> 6;
    const int lane = tid & 63;
    const int l15  = lane & 15;
    const int quad = lane >> 4;

    const int qt = blockIdx.x;
    const int bh = blockIdx.y;
    const int b  = bh >> 4;
    const int q0 = qt * BM;
    const int qrow = w * 16 + l15;

    const float* Qb = Qg + ((size_t)bh * S_LEN + q0) * D_DIM;
    const int*   Mb = Mg + (size_t)b * S_LEN;
    float* Ob = Og + ((size_t)bh * S_LEN + q0) * D_DIM;
    float* Ab = Ag + ((size_t)bh * S_LEN + q0) * (size_t)S_LEN;

    {
        const float sc = 0.04508422f;
        #pragma unroll
        for (int i = 0; i < 4; ++i) {
            int f = tid + i * 256;
            int row = f >> 4, c4 = f & 15;
            const float4 v = *(const float4*)(Qb + row * D_DIM + c4 * 4);
            *(uint2*)(&QV[row * LDP + c4 * 4]) =
                make_uint2(pack_bf16(v.x * sc, v.y * sc), pack_bf16(v.z * sc, v.w * sc));
        }
    }
    __syncthreads();

    bf16x8 aq[2];
    #pragma unroll
    for (int ks = 0; ks < 2; ++ks)
        aq[ks] = *(const bf16x8*)(&QV[qrow * LDP + ks * 32 + quad * 8]);

    auto stage_k = [&](int key0) {
        const float* Kb = Kg + ((size_t)bh * S_LEN + key0) * D_DIM;
        #pragma unroll
        for (int i = 0; i < 4; ++i) {
            int f = tid + i * 256;
            int row = f >> 4, c4 = f & 15;
            const float4 v = *(const float4*)(Kb + row * D_DIM + c4 * 4);
            *(uint2*)(&Ks[row * LDP + c4 * 4]) =
                make_uint2(pack_bf16(v.x, v.y), pack_bf16(v.z, v.w));
        }
    };

    float lsum = 0.f;
    for (int kt = 0; kt < NT; ++kt) {
        const int key0 = kt * BN;
        stage_k(key0);
        if (tid < BN) maskS[tid] = Mb[key0 + tid];
        __syncthreads();
        #pragma unroll
        for (int cb = 0; cb < 4; ++cb) {
            f32x4 acc = {0.f, 0.f, 0.f, 0.f};
            #pragma unroll
            for (int ks = 0; ks < 2; ++ks) {
                bf16x8 bk = *(const bf16x8*)(&Ks[(cb * 16 + l15) * LDP + ks * 32 + quad * 8]);
                acc = __builtin_amdgcn_mfma_f32_16x16x32_bf16(bk, aq[ks], acc, 0, 0, 0);
            }
            const int4 m4 = *(const int4*)(&maskS[cb * 16 + quad * 4]);
            float e0 = m4.x ? __builtin_exp2f(acc[0]) : 0.f;
            float e1 = m4.y ? __builtin_exp2f(acc[1]) : 0.f;
            float e2 = m4.z ? __builtin_exp2f(acc[2]) : 0.f;
            float e3 = m4.w ? __builtin_exp2f(acc[3]) : 0.f;
            lsum += (e0 + e1) + (e2 + e3);
        }
        __syncthreads();
    }
    lsum += __shfl_xor(lsum, 16);
    lsum += __shfl_xor(lsum, 32);
    const float linv = 1.0f / lsum;

    f32x4 oacc[4];
    #pragma unroll
    for (int db = 0; db < 4; ++db) oacc[db] = (f32x4){0.f, 0.f, 0.f, 0.f};

    for (int kt = 0; kt < NT; ++kt) {
        const int key0 = kt * BN;
        stage_k(key0);
        {
            int key = tid & 63, g = tid >> 6;
            #pragma unroll
            for (int i = 0; i < 4; ++i) {
                int d0 = (g * 4 + i) * 4;
                const float4 v = *(const float4*)(Vg + ((size_t)bh * S_LEN + key0 + key) * D_DIM + d0);
                QV[(d0 + 0) * LDP + key] = bf1(v.x);
                QV[(d0 + 1) * LDP + key] = bf1(v.y);
                QV[(d0 + 2) * LDP + key] = bf1(v.z);
                QV[(d0 + 3) * LDP + key] = bf1(v.w);
            }
        }
        if (tid < BN) maskS[tid] = Mb[key0 + tid];
        __syncthreads();

        #pragma unroll
        for (int cb = 0; cb < 4; ++cb) {
            f32x4 acc = {0.f, 0.f, 0.f, 0.f};
            #pragma unroll
            for (int ks = 0; ks < 2; ++ks) {
                bf16x8 bk = *(const bf16x8*)(&Ks[(cb * 16 + l15) * LDP + ks * 32 + quad * 8]);
                acc = __builtin_amdgcn_mfma_f32_16x16x32_bf16(bk, aq[ks], acc, 0, 0, 0);
            }
            const int4 m4 = *(const int4*)(&maskS[cb * 16 + quad * 4]);
            f32x4 p;
            p[0] = (m4.x ? __builtin_exp2f(acc[0]) : 0.f) * linv;
            p[1] = (m4.y ? __builtin_exp2f(acc[1]) : 0.f) * linv;
            p[2] = (m4.z ? __builtin_exp2f(acc[2]) : 0.f) * linv;
            p[3] = (m4.w ? __builtin_exp2f(acc[3]) : 0.f) * linv;
            *(f32x4*)(&Pf[qrow * 68 + cb * 16 + quad * 4]) = p;
        }
        #pragma unroll
        for (int ks2 = 0; ks2 < 2; ++ks2) {
            const float* pr = &Pf[qrow * 68 + ks2 * 32 + quad * 8];
            f32x4 pa = *(const f32x4*)(pr);
            f32x4 pb = *(const f32x4*)(pr + 4);
            union { bf16x8 v; uint4 u; } ap;
            ap.u.x = pack_bf16(pa[0], pa[1]);
            ap.u.y = pack_bf16(pa[2], pa[3]);
            ap.u.z = pack_bf16(pb[0], pb[1]);
            ap.u.w = pack_bf16(pb[2], pb[3]);
            #pragma unroll
            for (int db = 0; db < 4; ++db) {
                bf16x8 bv = *(const bf16x8*)(&QV[(db * 16 + l15) * LDP + ks2 * 32 + quad * 8]);
                oacc[db] = __builtin_amdgcn_mfma_f32_16x16x32_bf16(bv, ap.v, oacc[db], 0, 0, 0);
            }
        }
        __syncthreads();
        #pragma unroll
        for (int i = 0; i < 4; ++i) {
            int idx = tid + i * 256;
            int row = idx >> 4, c4 = idx & 15;
            f32x4 t = *(const f32x4*)(&Pf[row * 68 + c4 * 4]);
            __builtin_nontemporal_store(
                t, (f32x4*)(Ab + (size_t)row * S_LEN + key0 + c4 * 4));
        }
    }

    #pragma unroll
    for (int db = 0; db < 4; ++db) {
        f32x4 o4 = oacc[db];
        __builtin_nontemporal_store(
            o4, (f32x4*)(Ob + (size_t)qrow * D_DIM + db * 16 + quad * 4));
    }
}

extern "C" void kernel_launch(void* const* d_in, const int* in_sizes, int n_in,
                              void* d_out, int out_size, void* d_ws, size_t ws_size,
                              hipStream_t stream) {
    const float* q = (const float*)d_in[0];
    const float* k = (const float*)d_in[1];
    const float* v = (const float*)d_in[2];
    const int* mask = (const int*)d_in[3];
    float* out = (float*)d_out;                         // [B,H,S,D]
    float* attn = out + (size_t)2 * 16 * 2048 * 64;     // [B,H,S,S]

    const size_t kw_elems = (size_t)BH_N * S_LEN * D_DIM;        // 4.19M bf16
    const size_t need = 2 * kw_elems * sizeof(unsigned short);   // 16.8 MB
    dim3 block(256);
    dim3 grid(S_LEN / BM, BH_N);

    if (d_ws && ws_size >= need) {
        unsigned short* Kw  = (unsigned short*)d_ws;
        unsigned short* Vtw = Kw + kw_elems;
        conv_k<<<dim3((unsigned)(kw_elems / 8 / 256)), block, 0, stream>>>(k, Kw);
        conv_vt<<<dim3(S_LEN / 32, BH_N), block, 0, stream>>>(v, Vtw);
        attn_fast<<<grid, block, 0, stream>>>(q, mask, Kw, Vtw, out, attn);
    } else {
        attn_fallback<<<grid, block, 0, stream>>>(q, k, v, mask, out, attn);
    }
}

// Round 5
// 645.940 us; speedup vs baseline: 1.3347x; 1.1569x over previous
//
#include <hip/hip_runtime.h>
#include <hip/hip_bf16.h>

// B=2,H=16,S=2048,D=64 fp32 attention returning (output, attention).
// v6 = v3 (best: 644us total) + ONE change: lgkm-only barriers.
//     __syncthreads() on gfx950 emits "s_waitcnt vmcnt(0) lgkmcnt(0); s_barrier",
//     draining the previous tile's 16 nontemporal HBM P-stores (write-acks) and
//     all in-flight global loads at EVERY tile barrier (130/block). All cross-wave
//     deps here are through LDS, so "s_waitcnt lgkmcnt(0); s_barrier" suffices:
//     DS writes/reads covered per-wave, staged-load vmcnt deps are enforced at the
//     consuming ds_write by the compiler, and the global P/O stores are never read
//     (kernel-end release gives final visibility - v3's O store already relied on
//     this). Everything else is bit-identical to v3.

#define S_LEN 2048
#define D_DIM 64
#define BM 64
#define BN 64
#define NT (S_LEN / BN)   // 32 key tiles
#define LDP 72            // padded LDS row stride in bf16 elems (144 B)
#define LDF 68            // padded LDS row stride for fp32 P tile (272 B)
#define BH_N 32

typedef __attribute__((ext_vector_type(8))) short bf16x8;
typedef __attribute__((ext_vector_type(4))) float f32x4;

__device__ __forceinline__ unsigned pack_bf16(float a, float b) {
    union { __hip_bfloat162 h; unsigned u; } cv;
    cv.h = __float22bfloat162_rn(make_float2(a, b));   // v_cvt_pk_bf16_f32
    return cv.u;
}
__device__ __forceinline__ unsigned short bf1(float x) {
    union { __hip_bfloat16 h; unsigned short u; } cv;
    cv.h = __float2bfloat16(x);
    return cv.u;
}

// LDS-only barrier: waits this wave's DS ops, then syncs. Does NOT drain vmcnt,
// so nontemporal global stores and in-flight global loads span the barrier.
__device__ __forceinline__ void bar_lds() {
    asm volatile("s_waitcnt lgkmcnt(0)" ::: "memory");
    __builtin_amdgcn_s_barrier();
    asm volatile("" ::: "memory");
}

// ---- prepass: K fp32 -> bf16, same layout [bh][key][d] ----
__global__ __launch_bounds__(256)
void conv_k(const float* __restrict__ Kg, unsigned short* __restrict__ Kw) {
    size_t i = (size_t)(blockIdx.x * 256 + threadIdx.x) * 8;
    const float4 v0 = *(const float4*)(Kg + i);
    const float4 v1 = *(const float4*)(Kg + i + 4);
    uint4 o;
    o.x = pack_bf16(v0.x, v0.y);
    o.y = pack_bf16(v0.z, v0.w);
    o.z = pack_bf16(v1.x, v1.y);
    o.w = pack_bf16(v1.z, v1.w);
    *(uint4*)(Kw + i) = o;
}

// ---- prepass: V fp32 [bh][key][d] -> bf16 transposed [bh][d][key] ----
__global__ __launch_bounds__(256)
void conv_vt(const float* __restrict__ Vg, unsigned short* __restrict__ Vtw) {
    const int bh = blockIdx.y;
    const int d  = threadIdx.x & 63;
    const int kq = threadIdx.x >> 6;
    const int key0 = blockIdx.x * 32 + kq * 8;
    const float* Vb = Vg + ((size_t)bh * S_LEN + key0) * D_DIM + d;
    float f[8];
    #pragma unroll
    for (int i = 0; i < 8; ++i) f[i] = Vb[i * D_DIM];   // coalesced across d
    uint4 o;
    o.x = pack_bf16(f[0], f[1]);
    o.y = pack_bf16(f[2], f[3]);
    o.z = pack_bf16(f[4], f[5]);
    o.w = pack_bf16(f[6], f[7]);
    *(uint4*)(Vtw + ((size_t)bh * D_DIM + d) * S_LEN + key0) = o;
}

// PRE=1: K/V^T staged from pre-converted bf16 workspace. PRE=0: convert in-kernel.
template <int PRE>
__global__ __launch_bounds__(256, 4)
void attn_kernel(const float* __restrict__ Qg, const float* __restrict__ Kg,
                 const float* __restrict__ Vg, const int* __restrict__ Mg,
                 const unsigned short* __restrict__ Kw,
                 const unsigned short* __restrict__ Vtw,
                 float* __restrict__ Og, float* __restrict__ Ag) {
    __shared__ unsigned short Ks[BN * LDP];      // 9216 B
    __shared__ unsigned short QV[D_DIM * LDP];   // 9216 B: Q tile, then V^T tile
    __shared__ float Pf[BM * LDF];               // 17408 B: fp32 P tile
    __shared__ int maskS[BN];

    const int tid  = threadIdx.x;
    const int w    = tid >> 6;
    const int lane = tid & 63;
    const int l15  = lane & 15;
    const int quad = lane >> 4;

    const int qt = blockIdx.x;
    const int bh = blockIdx.y;
    const int b  = bh >> 4;
    const int q0 = qt * BM;
    const int qrow = w * 16 + l15;     // this lane's q row within the tile

    const float* Qb = Qg + ((size_t)bh * S_LEN + q0) * D_DIM;
    const int*   Mb = Mg + (size_t)b * S_LEN;
    float* Ob = Og + ((size_t)bh * S_LEN + q0) * D_DIM;
    float* Ab = Ag + ((size_t)bh * S_LEN + q0) * (size_t)S_LEN;

    // ---- stage Q scaled by log2(e)/32 (folds temperature AND exp->exp2) ----
    {
        const float sc = 0.04508422f;  // log2(e)/32
        #pragma unroll
        for (int i = 0; i < 4; ++i) {
            int f = tid + i * 256;
            int row = f >> 4, c4 = f & 15;
            const float4 v = *(const float4*)(Qb + row * D_DIM + c4 * 4);
            *(uint2*)(&QV[row * LDP + c4 * 4]) =
                make_uint2(pack_bf16(v.x * sc, v.y * sc), pack_bf16(v.z * sc, v.w * sc));
        }
    }
    bar_lds();

    // Q fragment, reused every tile in both passes (B-operand of swapped MFMA).
    bf16x8 aq[2];
    #pragma unroll
    for (int ks = 0; ks < 2; ++ks)
        aq[ks] = *(const bf16x8*)(&QV[qrow * LDP + ks * 32 + quad * 8]);
    // pass-1 barriers order these reads before pass-2 overwrites QV with V^T.

    auto stage_k = [&](int key0) {
        if constexpr (PRE) {
            const unsigned short* Kt = Kw + (size_t)bh * S_LEN * D_DIM + (size_t)key0 * D_DIM;
            #pragma unroll
            for (int i = 0; i < 2; ++i) {
                int idx = tid + i * 256;            // 512 chunks of 8 bf16
                int row = idx >> 3, c = idx & 7;
                uint4 vv = *(const uint4*)(Kt + row * D_DIM + c * 8);
                *(uint4*)(&Ks[row * LDP + c * 8]) = vv;
            }
        } else {
            const float* Kb = Kg + ((size_t)bh * S_LEN + key0) * D_DIM;
            #pragma unroll
            for (int i = 0; i < 4; ++i) {
                int f = tid + i * 256;
                int row = f >> 4, c4 = f & 15;
                const float4 v = *(const float4*)(Kb + row * D_DIM + c4 * 4);
                *(uint2*)(&Ks[row * LDP + c4 * 4]) =
                    make_uint2(pack_bf16(v.x, v.y), pack_bf16(v.z, v.w));
            }
        }
    };

    // ================= Pass 1: row sums of exp2(s) =================
    // Swapped MFMA: acc = K_frag * Q_frag -> D[row=key=quad*4+r][col=q=l15].
    float lsum = 0.f;

    for (int kt = 0; kt < NT; ++kt) {
        const int key0 = kt * BN;
        stage_k(key0);
        if (tid < BN) maskS[tid] = Mb[key0 + tid];
        bar_lds();

        #pragma unroll
        for (int cb = 0; cb < 4; ++cb) {
            f32x4 acc = {0.f, 0.f, 0.f, 0.f};
            #pragma unroll
            for (int ks = 0; ks < 2; ++ks) {
                bf16x8 bk = *(const bf16x8*)(&Ks[(cb * 16 + l15) * LDP + ks * 32 + quad * 8]);
                acc = __builtin_amdgcn_mfma_f32_16x16x32_bf16(bk, aq[ks], acc, 0, 0, 0);
            }
            const int4 m4 = *(const int4*)(&maskS[cb * 16 + quad * 4]);
            float e0 = m4.x ? __builtin_exp2f(acc[0]) : 0.f;
            float e1 = m4.y ? __builtin_exp2f(acc[1]) : 0.f;
            float e2 = m4.z ? __builtin_exp2f(acc[2]) : 0.f;
            float e3 = m4.w ? __builtin_exp2f(acc[3]) : 0.f;
            lsum += (e0 + e1) + (e2 + e3);
        }
        bar_lds();
    }

    // quads hold disjoint key subsets of the SAME q row -> 2-shuffle reduce
    lsum += __shfl_xor(lsum, 16);
    lsum += __shfl_xor(lsum, 32);
    const float linv = 1.0f / lsum;

    // ================= Pass 2: P -> LDS fp32, O += P V, coalesced P store ====
    f32x4 oacc[4];
    #pragma unroll
    for (int db = 0; db < 4; ++db) oacc[db] = (f32x4){0.f, 0.f, 0.f, 0.f};

    for (int kt = 0; kt < NT; ++kt) {
        const int key0 = kt * BN;
        stage_k(key0);
        if constexpr (PRE) {
            const unsigned short* Vt = Vtw + (size_t)bh * D_DIM * S_LEN + key0;
            #pragma unroll
            for (int i = 0; i < 2; ++i) {
                int idx = tid + i * 256;
                int d = idx >> 3, c = idx & 7;
                uint4 vv = *(const uint4*)(Vt + (size_t)d * S_LEN + c * 8);
                *(uint4*)(&QV[d * LDP + c * 8]) = vv;
            }
        } else {
            int key = tid & 63, g = tid >> 6;
            #pragma unroll
            for (int i = 0; i < 4; ++i) {
                int d0 = (g * 4 + i) * 4;
                const float4 v = *(const float4*)(Vg + ((size_t)bh * S_LEN + key0 + key) * D_DIM + d0);
                QV[(d0 + 0) * LDP + key] = bf1(v.x);
                QV[(d0 + 1) * LDP + key] = bf1(v.y);
                QV[(d0 + 2) * LDP + key] = bf1(v.z);
                QV[(d0 + 3) * LDP + key] = bf1(v.w);
            }
        }
        if (tid < BN) maskS[tid] = Mb[key0 + tid];
        // Barrier also orders the previous tile's cooperative Pf reads before
        // this tile's Pf writes in the cb loop below.
        bar_lds();

        #pragma unroll
        for (int cb = 0; cb < 4; ++cb) {
            f32x4 acc = {0.f, 0.f, 0.f, 0.f};
            #pragma unroll
            for (int ks = 0; ks < 2; ++ks) {
                bf16x8 bk = *(const bf16x8*)(&Ks[(cb * 16 + l15) * LDP + ks * 32 + quad * 8]);
                acc = __builtin_amdgcn_mfma_f32_16x16x32_bf16(bk, aq[ks], acc, 0, 0, 0);
            }
            const int4 m4 = *(const int4*)(&maskS[cb * 16 + quad * 4]);
            f32x4 p;
            p[0] = (m4.x ? __builtin_exp2f(acc[0]) : 0.f) * linv;
            p[1] = (m4.y ? __builtin_exp2f(acc[1]) : 0.f) * linv;
            p[2] = (m4.z ? __builtin_exp2f(acc[2]) : 0.f) * linv;
            p[3] = (m4.w ? __builtin_exp2f(acc[3]) : 0.f) * linv;
            *(f32x4*)(&Pf[qrow * LDF + cb * 16 + quad * 4]) = p;
        }

        // PV (swapped: A=V^T frag, B=P frag built from fp32 Pf rows via cvt_pk).
        // Pf rows for wave w written only by wave w -> same-wave RAW, no barrier.
        #pragma unroll
        for (int ks2 = 0; ks2 < 2; ++ks2) {
            const float* pr = &Pf[qrow * LDF + ks2 * 32 + quad * 8];
            f32x4 pa = *(const f32x4*)(pr);
            f32x4 pb = *(const f32x4*)(pr + 4);
            union { bf16x8 v; uint4 u; } ap;
            ap.u.x = pack_bf16(pa[0], pa[1]);
            ap.u.y = pack_bf16(pa[2], pa[3]);
            ap.u.z = pack_bf16(pb[0], pb[1]);
            ap.u.w = pack_bf16(pb[2], pb[3]);
            #pragma unroll
            for (int db = 0; db < 4; ++db) {
                bf16x8 bv = *(const bf16x8*)(&QV[(db * 16 + l15) * LDP + ks2 * 32 + quad * 8]);
                oacc[db] = __builtin_amdgcn_mfma_f32_16x16x32_bf16(bv, ap.v, oacc[db], 0, 0, 0);
            }
        }
        bar_lds();   // Pf fully written; also K/QV reads done before restage

        // Cooperative coalesced P store: each wave instr = 4 rows x 256B segments.
        // Overlaps with next iteration's staging loads (no barrier in between),
        // and with lgkm-only barriers the store-acks never stall a barrier.
        #pragma unroll
        for (int i = 0; i < 4; ++i) {
            int idx = tid + i * 256;           // 0..1023 float4 chunks
            int row = idx >> 4, c4 = idx & 15;
            f32x4 t = *(const f32x4*)(&Pf[row * LDF + c4 * 4]);
            __builtin_nontemporal_store(
                t, (f32x4*)(Ab + (size_t)row * S_LEN + key0 + c4 * 4));
        }
    }

    // write O: lane holds d = db*16 + quad*4 + r for row qrow -> float4 stores
    #pragma unroll
    for (int db = 0; db < 4; ++db) {
        f32x4 o4 = oacc[db];
        __builtin_nontemporal_store(
            o4, (f32x4*)(Ob + (size_t)qrow * D_DIM + db * 16 + quad * 4));
    }
}

extern "C" void kernel_launch(void* const* d_in, const int* in_sizes, int n_in,
                              void* d_out, int out_size, void* d_ws, size_t ws_size,
                              hipStream_t stream) {
    const float* q = (const float*)d_in[0];
    const float* k = (const float*)d_in[1];
    const float* v = (const float*)d_in[2];
    const int* mask = (const int*)d_in[3];
    float* out = (float*)d_out;                         // [B,H,S,D]
    float* attn = out + (size_t)2 * 16 * 2048 * 64;     // [B,H,S,S]

    const size_t kw_elems = (size_t)BH_N * S_LEN * D_DIM;        // 4.19M bf16
    const size_t need = 2 * kw_elems * sizeof(unsigned short);   // 16.8 MB
    dim3 block(256);
    dim3 grid(S_LEN / BM, BH_N);

    if (d_ws && ws_size >= need) {
        unsigned short* Kw  = (unsigned short*)d_ws;
        unsigned short* Vtw = Kw + kw_elems;
        conv_k<<<dim3((unsigned)(kw_elems / 8 / 256)), block, 0, stream>>>(k, Kw);
        conv_vt<<<dim3(S_LEN / 32, BH_N), block, 0, stream>>>(v, Vtw);
        attn_kernel<1><<<grid, block, 0, stream>>>(q, k, v, mask, Kw, Vtw, out, attn);
    } else {
        attn_kernel<0><<<grid, block, 0, stream>>>(q, k, v, mask, nullptr, nullptr, out, attn);
    }
}

// Round 7
// 636.793 us; speedup vs baseline: 1.3538x; 1.0144x over previous
//
#include <hip/hip_runtime.h>
#include <hip/hip_bf16.h>

// B=2,H=16,S=2048,D=64 fp32 attention returning (output, attention).
// v8 = v6 structure (best passing: 644-646us) + ONE mechanism: 2-tile write
//     combining. P for a PAIR of 64-key tiles accumulates in a bf16 LDS tile
//     Pb[64][136] (17.4KB, replaces the fp32 Pf of equal size; LDS stays 36KB
//     -> 4 blocks/CU), and the attention store flushes once per pair as
//     64 rows x 512B contiguous segments (was 256B) -> better HBM page
//     locality on the 537MB stream (fill kernel does 6.2TB/s sequential vs
//     our ~2.2TB/s scattered). PV fragments read the bf16 Pb directly (same
//     bits as v3's cvt_pk path -> O unchanged; A gains <=2e-5 bf16 rounding,
//     numerically validated by v7's passing first check). Plain __syncthreads
//     everywhere (lgkm-only barriers measured worth 0 in v6). Prepass
//     K->bf16 / V->bf16^T in d_ws kept.

#define S_LEN 2048
#define D_DIM 64
#define BM 64
#define BN 64
#define NT (S_LEN / BN)   // 32 key tiles (even -> 16 pairs)
#define LDP 72            // bf16 row stride for K/Q/V tiles (144 B)
#define PSTR 136          // bf16 row stride for P pair-tile (272 B, 16B-aligned)
#define BH_N 32

typedef __attribute__((ext_vector_type(8))) short bf16x8;
typedef __attribute__((ext_vector_type(4))) float f32x4;

__device__ __forceinline__ unsigned pack_bf16(float a, float b) {
    union { __hip_bfloat162 h; unsigned u; } cv;
    cv.h = __float22bfloat162_rn(make_float2(a, b));   // v_cvt_pk_bf16_f32
    return cv.u;
}
__device__ __forceinline__ unsigned short bf1(float x) {
    union { __hip_bfloat16 h; unsigned short u; } cv;
    cv.h = __float2bfloat16(x);
    return cv.u;
}
__device__ __forceinline__ float bf2f(unsigned bits) {
    return __uint_as_float(bits);
}

// ---- prepass: K fp32 -> bf16, same layout [bh][key][d] ----
__global__ __launch_bounds__(256)
void conv_k(const float* __restrict__ Kg, unsigned short* __restrict__ Kw) {
    size_t i = (size_t)(blockIdx.x * 256 + threadIdx.x) * 8;
    const float4 v0 = *(const float4*)(Kg + i);
    const float4 v1 = *(const float4*)(Kg + i + 4);
    uint4 o;
    o.x = pack_bf16(v0.x, v0.y);
    o.y = pack_bf16(v0.z, v0.w);
    o.z = pack_bf16(v1.x, v1.y);
    o.w = pack_bf16(v1.z, v1.w);
    *(uint4*)(Kw + i) = o;
}

// ---- prepass: V fp32 [bh][key][d] -> bf16 transposed [bh][d][key] ----
__global__ __launch_bounds__(256)
void conv_vt(const float* __restrict__ Vg, unsigned short* __restrict__ Vtw) {
    const int bh = blockIdx.y;
    const int d  = threadIdx.x & 63;
    const int kq = threadIdx.x >> 6;
    const int key0 = blockIdx.x * 32 + kq * 8;
    const float* Vb = Vg + ((size_t)bh * S_LEN + key0) * D_DIM + d;
    float f[8];
    #pragma unroll
    for (int i = 0; i < 8; ++i) f[i] = Vb[i * D_DIM];   // coalesced across d
    uint4 o;
    o.x = pack_bf16(f[0], f[1]);
    o.y = pack_bf16(f[2], f[3]);
    o.z = pack_bf16(f[4], f[5]);
    o.w = pack_bf16(f[6], f[7]);
    *(uint4*)(Vtw + ((size_t)bh * D_DIM + d) * S_LEN + key0) = o;
}

// PRE=1: K/V^T staged from pre-converted bf16 workspace. PRE=0: convert in-kernel.
template <int PRE>
__global__ __launch_bounds__(256, 4)
void attn_kernel(const float* __restrict__ Qg, const float* __restrict__ Kg,
                 const float* __restrict__ Vg, const int* __restrict__ Mg,
                 const unsigned short* __restrict__ Kw,
                 const unsigned short* __restrict__ Vtw,
                 float* __restrict__ Og, float* __restrict__ Ag) {
    __shared__ unsigned short Ks[BN * LDP];      // 9216 B  K tile [key][d]
    __shared__ unsigned short QV[D_DIM * LDP];   // 9216 B  Q tile, then V^T tile
    __shared__ unsigned short Pb[BM * PSTR];     // 17408 B bf16 P pair-tile [q][128key]
    __shared__ int maskS[BN];

    const int tid  = threadIdx.x;
    const int w    = tid >> 6;
    const int lane = tid & 63;
    const int l15  = lane & 15;
    const int quad = lane >> 4;

    const int qt = blockIdx.x;
    const int bh = blockIdx.y;
    const int b  = bh >> 4;
    const int q0 = qt * BM;
    const int qrow = w * 16 + l15;     // this lane's q row within the tile

    const float* Qb = Qg + ((size_t)bh * S_LEN + q0) * D_DIM;
    const int*   Mb = Mg + (size_t)b * S_LEN;
    float* Ob = Og + ((size_t)bh * S_LEN + q0) * D_DIM;
    float* Ab = Ag + ((size_t)bh * S_LEN + q0) * (size_t)S_LEN;

    // ---- stage Q scaled by log2(e)/32 (folds temperature AND exp->exp2) ----
    {
        const float sc = 0.04508422f;  // log2(e)/32
        #pragma unroll
        for (int i = 0; i < 4; ++i) {
            int f = tid + i * 256;
            int row = f >> 4, c4 = f & 15;
            const float4 v = *(const float4*)(Qb + row * D_DIM + c4 * 4);
            *(uint2*)(&QV[row * LDP + c4 * 4]) =
                make_uint2(pack_bf16(v.x * sc, v.y * sc), pack_bf16(v.z * sc, v.w * sc));
        }
    }
    __syncthreads();

    // Q fragment, reused every tile in both passes (B-operand of swapped MFMA).
    bf16x8 aq[2];
    #pragma unroll
    for (int ks = 0; ks < 2; ++ks)
        aq[ks] = *(const bf16x8*)(&QV[qrow * LDP + ks * 32 + quad * 8]);
    // pass-1 barriers order these reads before pass-2 overwrites QV with V^T.

    auto stage_k = [&](int key0) {
        if constexpr (PRE) {
            const unsigned short* Kt = Kw + (size_t)bh * S_LEN * D_DIM + (size_t)key0 * D_DIM;
            #pragma unroll
            for (int i = 0; i < 2; ++i) {
                int idx = tid + i * 256;            // 512 chunks of 8 bf16
                int row = idx >> 3, c = idx & 7;
                uint4 vv = *(const uint4*)(Kt + row * D_DIM + c * 8);
                *(uint4*)(&Ks[row * LDP + c * 8]) = vv;
            }
        } else {
            const float* Kb = Kg + ((size_t)bh * S_LEN + key0) * D_DIM;
            #pragma unroll
            for (int i = 0; i < 4; ++i) {
                int f = tid + i * 256;
                int row = f >> 4, c4 = f & 15;
                const float4 v = *(const float4*)(Kb + row * D_DIM + c4 * 4);
                *(uint2*)(&Ks[row * LDP + c4 * 4]) =
                    make_uint2(pack_bf16(v.x, v.y), pack_bf16(v.z, v.w));
            }
        }
    };
    auto stage_v = [&](int key0) {
        if constexpr (PRE) {
            const unsigned short* Vt = Vtw + (size_t)bh * D_DIM * S_LEN + key0;
            #pragma unroll
            for (int i = 0; i < 2; ++i) {
                int idx = tid + i * 256;
                int d = idx >> 3, c = idx & 7;
                uint4 vv = *(const uint4*)(Vt + (size_t)d * S_LEN + c * 8);
                *(uint4*)(&QV[d * LDP + c * 8]) = vv;
            }
        } else {
            int key = tid & 63, g = tid >> 6;
            #pragma unroll
            for (int i = 0; i < 4; ++i) {
                int d0 = (g * 4 + i) * 4;
                const float4 v = *(const float4*)(Vg + ((size_t)bh * S_LEN + key0 + key) * D_DIM + d0);
                QV[(d0 + 0) * LDP + key] = bf1(v.x);
                QV[(d0 + 1) * LDP + key] = bf1(v.y);
                QV[(d0 + 2) * LDP + key] = bf1(v.z);
                QV[(d0 + 3) * LDP + key] = bf1(v.w);
            }
        }
    };

    // ================= Pass 1: row sums of exp2(s) =================
    // Swapped MFMA: acc = K_frag * Q_frag -> D[row=key=quad*4+r][col=q=l15].
    float lsum = 0.f;

    for (int kt = 0; kt < NT; ++kt) {
        const int key0 = kt * BN;
        stage_k(key0);
        if (tid < BN) maskS[tid] = Mb[key0 + tid];
        __syncthreads();

        #pragma unroll
        for (int cb = 0; cb < 4; ++cb) {
            f32x4 acc = {0.f, 0.f, 0.f, 0.f};
            #pragma unroll
            for (int ks = 0; ks < 2; ++ks) {
                bf16x8 bk = *(const bf16x8*)(&Ks[(cb * 16 + l15) * LDP + ks * 32 + quad * 8]);
                acc = __builtin_amdgcn_mfma_f32_16x16x32_bf16(bk, aq[ks], acc, 0, 0, 0);
            }
            const int4 m4 = *(const int4*)(&maskS[cb * 16 + quad * 4]);
            float e0 = m4.x ? __builtin_exp2f(acc[0]) : 0.f;
            float e1 = m4.y ? __builtin_exp2f(acc[1]) : 0.f;
            float e2 = m4.z ? __builtin_exp2f(acc[2]) : 0.f;
            float e3 = m4.w ? __builtin_exp2f(acc[3]) : 0.f;
            lsum += (e0 + e1) + (e2 + e3);
        }
        __syncthreads();
    }

    // quads hold disjoint key subsets of the SAME q row -> 2-shuffle reduce
    lsum += __shfl_xor(lsum, 16);
    lsum += __shfl_xor(lsum, 32);
    const float linv = 1.0f / lsum;

    // ================= Pass 2: pair loop, P bf16 in Pb, 512B A-flush =========
    f32x4 oacc[4];
    #pragma unroll
    for (int db = 0; db < 4; ++db) oacc[db] = (f32x4){0.f, 0.f, 0.f, 0.f};

    for (int kt2 = 0; kt2 < NT / 2; ++kt2) {
        #pragma unroll
        for (int half = 0; half < 2; ++half) {
            const int key0 = (kt2 * 2 + half) * BN;
            stage_k(key0);
            stage_v(key0);
            if (tid < BN) maskS[tid] = Mb[key0 + tid];
            // Barrier also orders prev pair's cooperative Pb reads (drained by
            // each wave's own syncthreads) before this half's Pb writes below.
            __syncthreads();

            // QK^T -> exp2 -> normalized bf16 P into this half's columns.
            #pragma unroll
            for (int cb = 0; cb < 4; ++cb) {
                f32x4 acc = {0.f, 0.f, 0.f, 0.f};
                #pragma unroll
                for (int ks = 0; ks < 2; ++ks) {
                    bf16x8 bk = *(const bf16x8*)(&Ks[(cb * 16 + l15) * LDP + ks * 32 + quad * 8]);
                    acc = __builtin_amdgcn_mfma_f32_16x16x32_bf16(bk, aq[ks], acc, 0, 0, 0);
                }
                const int4 m4 = *(const int4*)(&maskS[cb * 16 + quad * 4]);
                float p0 = (m4.x ? __builtin_exp2f(acc[0]) : 0.f) * linv;
                float p1 = (m4.y ? __builtin_exp2f(acc[1]) : 0.f) * linv;
                float p2 = (m4.z ? __builtin_exp2f(acc[2]) : 0.f) * linv;
                float p3 = (m4.w ? __builtin_exp2f(acc[3]) : 0.f) * linv;
                *(uint2*)(&Pb[qrow * PSTR + half * 64 + cb * 16 + quad * 4]) =
                    make_uint2(pack_bf16(p0, p1), pack_bf16(p2, p3));
            }

            // PV: A = V^T frag, B = bf16 P frag read back from this wave's OWN
            // Pb rows (same-wave RAW -> compiler lgkmcnt; same bits as cvt_pk).
            #pragma unroll
            for (int ks2 = 0; ks2 < 2; ++ks2) {
                bf16x8 ap = *(const bf16x8*)(&Pb[qrow * PSTR + half * 64 + ks2 * 32 + quad * 8]);
                #pragma unroll
                for (int db = 0; db < 4; ++db) {
                    bf16x8 bv = *(const bf16x8*)(&QV[(db * 16 + l15) * LDP + ks2 * 32 + quad * 8]);
                    oacc[db] = __builtin_amdgcn_mfma_f32_16x16x32_bf16(bv, ap, oacc[db], 0, 0, 0);
                }
            }
            __syncthreads();   // half fully written; Ks/QV reads done before restage
        }

        // Cooperative A-flush of the pair: 64 rows x 128 keys. Each 32-lane
        // half-wave writes 512B contiguous (16B/lane) -> 2x the segment size
        // of the per-tile flush. Overlaps next pair's staging loads.
        const int key00 = kt2 * 2 * BN;
        #pragma unroll
        for (int i = 0; i < 8; ++i) {
            int idx = tid + i * 256;          // 0..2047 uint2 chunks of 4 bf16
            int row = idx >> 5, c4 = idx & 31;
            uint2 pu = *(const uint2*)(&Pb[row * PSTR + c4 * 4]);
            f32x4 t;
            t[0] = bf2f(pu.x << 16); t[1] = bf2f(pu.x & 0xffff0000u);
            t[2] = bf2f(pu.y << 16); t[3] = bf2f(pu.y & 0xffff0000u);
            __builtin_nontemporal_store(
                t, (f32x4*)(Ab + (size_t)row * S_LEN + key00 + c4 * 4));
        }
    }

    // write O: lane holds d = db*16 + quad*4 + r for row qrow -> float4 stores
    #pragma unroll
    for (int db = 0; db < 4; ++db) {
        f32x4 o4 = oacc[db];
        __builtin_nontemporal_store(
            o4, (f32x4*)(Ob + (size_t)qrow * D_DIM + db * 16 + quad * 4));
    }
}

extern "C" void kernel_launch(void* const* d_in, const int* in_sizes, int n_in,
                              void* d_out, int out_size, void* d_ws, size_t ws_size,
                              hipStream_t stream) {
    const float* q = (const float*)d_in[0];
    const float* k = (const float*)d_in[1];
    const float* v = (const float*)d_in[2];
    const int* mask = (const int*)d_in[3];
    float* out = (float*)d_out;                         // [B,H,S,D]
    float* attn = out + (size_t)2 * 16 * 2048 * 64;     // [B,H,S,S]

    const size_t kw_elems = (size_t)BH_N * S_LEN * D_DIM;        // 4.19M bf16
    const size_t need = 2 * kw_elems * sizeof(unsigned short);   // 16.8 MB
    dim3 block(256);
    dim3 grid(S_LEN / BM, BH_N);

    if (d_ws && ws_size >= need) {
        unsigned short* Kw  = (unsigned short*)d_ws;
        unsigned short* Vtw = Kw + kw_elems;
        conv_k<<<dim3((unsigned)(kw_elems / 8 / 256)), block, 0, stream>>>(k, Kw);
        conv_vt<<<dim3(S_LEN / 32, BH_N), block, 0, stream>>>(v, Vtw);
        attn_kernel<1><<<grid, block, 0, stream>>>(q, k, v, mask, Kw, Vtw, out, attn);
    } else {
        attn_kernel<0><<<grid, block, 0, stream>>>(q, k, v, mask, nullptr, nullptr, out, attn);
    }
}